// Round 7
// baseline (199.027 us; speedup 1.0000x reference)
//
#include <hip/hip_runtime.h>

typedef float f32x2 __attribute__((ext_vector_type(2)));
typedef float f32x4 __attribute__((ext_vector_type(4)));

#define BB 4
#define NN 8192
#define NPTS (BB * NN)            // 32768 per cloud; total mins = 2*NPTS
#define TILE 256
#define RI 4                      // self points per thread
#define SELF_PER_BLOCK (TILE * RI)      // 1024
#define STILES (NN / SELF_PER_BLOCK)    // 8
#define JSPLIT 16
#define JRANGE (NN / JSPLIT)            // 512 j per block window
#define JPAIRS (JRANGE / 2)             // 256 staged pairs
#define TOTAL_BLOCKS (STILES * JSPLIT * 2 * BB)   // 1024

// ws layout: [0] uint arrival counter ; [1024B ..] pm = uint[2*BB][NN] (256 KB)
// Both initialized by ONE hipMemsetAsync(0xFF):
//   pm: 0xFFFFFFFF = +inf sentinel for uint-bits atomicMin (all dists >= 0)
//   counter: starts at 0xFFFFFFFF, so the n-th atomicAdd RETURNS n-2;
//            the last of TOTAL_BLOCKS arrivals sees TOTAL_BLOCKS-2.
__global__ __launch_bounds__(TILE) void chamfer_fused(
    const float* __restrict__ p1, const float* __restrict__ p2,
    unsigned* __restrict__ ws_counter, unsigned* __restrict__ pm,
    float* __restrict__ out)
{
    const int bz  = blockIdx.y;            // 0..7 = {b,dir}
    const int b   = bz >> 1;
    const int dir = bz & 1;                // 0: self=p1,other=p2
    const int stile = blockIdx.x >> 4;     // 0..7
    const int js    = blockIdx.x & 15;     // 0..15

    const float* selfp  = dir ? p2 : p1;
    const float* otherp = dir ? p1 : p2;

    // ---- Stage + transform the j-window (512 pts) pair-packed into LDS ----
    // soA[jp] = (-2x0,-2x1,-2y0,-2y1)   soB[jp] = (-2z0,-2z1,|q0|^2,|q1|^2)
    __shared__ f32x4 soA[JPAIRS];
    __shared__ f32x4 soB[JPAIRS];
    {
        const float2* src = reinterpret_cast<const float2*>(
            otherp + ((size_t)b * NN + (size_t)js * JRANGE) * 3);
        const int t = threadIdx.x;         // pair id, 256 pairs
        const float2 u = src[3*t], v = src[3*t+1], w = src[3*t+2];
        const float x0=u.x, y0=u.y, z0=v.x, x1=v.y, y1=w.x, z1=w.y;
        soA[t] = f32x4{-2.f*x0, -2.f*x1, -2.f*y0, -2.f*y1};
        soB[t] = f32x4{-2.f*z0, -2.f*z1,
                       fmaf(x0,x0,fmaf(y0,y0,z0*z0)),
                       fmaf(x1,x1,fmaf(y1,y1,z1*z1))};
    }

    // ---- Self points: RI=4 per thread ----
    const int i0 = stile * SELF_PER_BLOCK + threadIdx.x;
    float ax[RI], ay[RI], az[RI], a2[RI];
    #pragma unroll
    for (int s = 0; s < RI; ++s) {
        const float* sp = selfp + ((size_t)b * NN + i0 + s * TILE) * 3;
        ax[s] = sp[0]; ay[s] = sp[1]; az[s] = sp[2];
        a2[s] = fmaf(ax[s],ax[s], fmaf(ay[s],ay[s], az[s]*az[s]));
    }
    __syncthreads();

    // ---- Main scan: 256 pair-iterations, broadcast LDS reads ----
    f32x2 m0 = {3.4e38f, 3.4e38f}, m1 = m0, m2 = m0, m3 = m0;
    #pragma unroll 4
    for (int kp = 0; kp < JPAIRS; ++kp) {
        const f32x4 A = soA[kp];
        const f32x4 B = soB[kp];
        const f32x2 qx = A.xy, qy = A.zw, qz = B.xy, qw = B.zw;
        f32x2 v;
        v = __builtin_elementwise_fma(f32x2{ax[0],ax[0]}, qx,
            __builtin_elementwise_fma(f32x2{ay[0],ay[0]}, qy,
            __builtin_elementwise_fma(f32x2{az[0],az[0]}, qz, qw)));
        m0 = __builtin_elementwise_min(m0, v);
        v = __builtin_elementwise_fma(f32x2{ax[1],ax[1]}, qx,
            __builtin_elementwise_fma(f32x2{ay[1],ay[1]}, qy,
            __builtin_elementwise_fma(f32x2{az[1],az[1]}, qz, qw)));
        m1 = __builtin_elementwise_min(m1, v);
        v = __builtin_elementwise_fma(f32x2{ax[2],ax[2]}, qx,
            __builtin_elementwise_fma(f32x2{ay[2],ay[2]}, qy,
            __builtin_elementwise_fma(f32x2{az[2],az[2]}, qz, qw)));
        m2 = __builtin_elementwise_min(m2, v);
        v = __builtin_elementwise_fma(f32x2{ax[3],ax[3]}, qx,
            __builtin_elementwise_fma(f32x2{ay[3],ay[3]}, qy,
            __builtin_elementwise_fma(f32x2{az[3],az[3]}, qz, qw)));
        m3 = __builtin_elementwise_min(m3, v);
    }

    // ---- Window-partial results -> atomicMin (uint bits, dists >= 0) ----
    {
        const float r0 = fmaxf(fminf(m0.x,m0.y) + a2[0], 0.f);
        const float r1 = fmaxf(fminf(m1.x,m1.y) + a2[1], 0.f);
        const float r2 = fmaxf(fminf(m2.x,m2.y) + a2[2], 0.f);
        const float r3 = fmaxf(fminf(m3.x,m3.y) + a2[3], 0.f);
        unsigned* row = pm + (size_t)bz * NN + i0;
        atomicMin(&row[0*TILE], __float_as_uint(r0));
        atomicMin(&row[1*TILE], __float_as_uint(r1));
        atomicMin(&row[2*TILE], __float_as_uint(r2));
        atomicMin(&row[3*TILE], __float_as_uint(r3));
    }

    // ---- Last-arriving block reduces pm -> out[0] ----
    __shared__ unsigned is_last;
    __threadfence();                          // make our mins visible
    if (threadIdx.x == 0) {
        const unsigned old = atomicAdd(ws_counter, 1u);
        is_last = (old == (unsigned)(TOTAL_BLOCKS - 2)) ? 1u : 0u;  // see header note
    }
    __syncthreads();
    if (is_last) {
        __threadfence();                      // acquire all blocks' mins
        float ssum = 0.f;
        const volatile unsigned* pv = pm;
        for (int i = threadIdx.x; i < 2 * BB * NN; i += TILE)
            ssum += __uint_as_float(pv[i]);
        #pragma unroll
        for (int off = 32; off; off >>= 1) ssum += __shfl_down(ssum, off);
        __shared__ float wsum[TILE / 64];
        const int lane = threadIdx.x & 63, wid = threadIdx.x >> 6;
        if (lane == 0) wsum[wid] = ssum;
        __syncthreads();
        if (threadIdx.x == 0) {
            float t = 0.f;
            #pragma unroll
            for (int w = 0; w < TILE / 64; ++w) t += wsum[w];
            out[0] = t * (1.f / (float)NPTS);
        }
    }
}

extern "C" void kernel_launch(void* const* d_in, const int* in_sizes, int n_in,
                              void* d_out, int out_size, void* d_ws, size_t ws_size,
                              hipStream_t stream)
{
    const float* p1 = (const float*)d_in[0];
    const float* p2 = (const float*)d_in[1];
    unsigned* counter = (unsigned*)d_ws;
    unsigned* pm      = (unsigned*)((char*)d_ws + 1024);
    float* out        = (float*)d_out;

    // One memset inits BOTH counter (0xFFFFFFFF) and pm (+inf sentinels).
    hipMemsetAsync(d_ws, 0xFF, 1024 + (size_t)2 * BB * NN * sizeof(unsigned), stream);

    dim3 grid(STILES * JSPLIT, 2 * BB);       // 128 x 8 = 1024 blocks
    chamfer_fused<<<grid, TILE, 0, stream>>>(p1, p2, counter, pm, out);
}

// Round 8
// 102.917 us; speedup vs baseline: 1.9339x; 1.9339x over previous
//
#include <hip/hip_runtime.h>

typedef float f32x2 __attribute__((ext_vector_type(2)));
typedef float f32x4 __attribute__((ext_vector_type(4)));

#define BB 4
#define NN 8192
#define NPTS (BB * NN)                  // 32768 per cloud
#define TILE 256
#define RI 8                            // self points per thread
#define SELF_PER_BLOCK (TILE * RI)      // 2048
#define STILES (NN / SELF_PER_BLOCK)    // 4
#define JSPLIT 32                       // j-windows per (b,dir)
#define JRANGE (NN / JSPLIT)            // 256 j per window
#define JPAIRS (JRANGE / 2)             // 128 staged pairs (4 KB LDS)
#define RBLOCKS 64                      // reduce-kernel blocks

// Main: each block = one (b, dir, self-tile of 2048, j-window of 256).
// q-window pair-packed in LDS; each thread: RI=8 self pts, scans all 128
// pairs via 2 broadcast ds_read_b128 + 32 pk-VALU per pair-iter.
// Deterministic: partial mins (with +|a|^2, clamped) stored to pm[bz][js][i].
__global__ __launch_bounds__(TILE) void chamfer_main(
    const float* __restrict__ p1, const float* __restrict__ p2,
    float* __restrict__ pm)
{
    const int bz  = blockIdx.y;             // 0..7
    const int b   = bz >> 1;
    const int dir = bz & 1;                 // 0: self=p1, other=p2
    const int stile = blockIdx.x >> 5;      // 0..3   (JSPLIT=32)
    const int js    = blockIdx.x & 31;      // 0..31

    const float* selfp  = dir ? p2 : p1;
    const float* otherp = dir ? p1 : p2;

    // ---- Stage j-window pair-packed into LDS ----
    // soA[jp] = (-2x0,-2x1,-2y0,-2y1)  soB[jp] = (-2z0,-2z1,|q0|^2,|q1|^2)
    __shared__ f32x4 soA[JPAIRS];
    __shared__ f32x4 soB[JPAIRS];
    if (threadIdx.x < JPAIRS) {
        const int t = threadIdx.x;
        const float2* src = reinterpret_cast<const float2*>(
            otherp + ((size_t)b * NN + (size_t)js * JRANGE) * 3);
        const float2 u = src[3*t], v = src[3*t+1], w = src[3*t+2];
        const float x0=u.x, y0=u.y, z0=v.x, x1=v.y, y1=w.x, z1=w.y;
        soA[t] = f32x4{-2.f*x0, -2.f*x1, -2.f*y0, -2.f*y1};
        soB[t] = f32x4{-2.f*z0, -2.f*z1,
                       fmaf(x0,x0,fmaf(y0,y0,z0*z0)),
                       fmaf(x1,x1,fmaf(y1,y1,z1*z1))};
    }

    // ---- Self points (RI per thread, strided TILE) ----
    const int i0 = stile * SELF_PER_BLOCK + threadIdx.x;
    float ax[RI], ay[RI], az[RI];
    #pragma unroll
    for (int s = 0; s < RI; ++s) {
        const float* sp = selfp + ((size_t)b * NN + i0 + s * TILE) * 3;
        ax[s] = sp[0]; ay[s] = sp[1]; az[s] = sp[2];
    }
    __syncthreads();

    // ---- Main scan: 128 pair-iters; all indices compile-time constant ----
    f32x2 m[RI];
    #pragma unroll
    for (int s = 0; s < RI; ++s) m[s] = f32x2{3.4e38f, 3.4e38f};

    #pragma unroll 2
    for (int kp = 0; kp < JPAIRS; ++kp) {
        const f32x4 A = soA[kp];
        const f32x4 B = soB[kp];
        const f32x2 qx = A.xy, qy = A.zw, qz = B.xy, qw = B.zw;
        #pragma unroll
        for (int s = 0; s < RI; ++s) {
            const f32x2 v = __builtin_elementwise_fma(f32x2{ax[s],ax[s]}, qx,
                            __builtin_elementwise_fma(f32x2{ay[s],ay[s]}, qy,
                            __builtin_elementwise_fma(f32x2{az[s],az[s]}, qz, qw)));
            m[s] = __builtin_elementwise_min(m[s], v);
        }
    }

    // ---- Epilogue: +|a|^2, clamp, plain store (no atomics) ----
    float* row = pm + ((size_t)bz * JSPLIT + js) * NN + i0;
    #pragma unroll
    for (int s = 0; s < RI; ++s) {
        const float a2 = fmaf(ax[s],ax[s], fmaf(ay[s],ay[s], az[s]*az[s]));
        row[s * TILE] = fmaxf(fminf(m[s].x, m[s].y) + a2, 0.f);
    }
}

// Reduce 1: per (bz,i) min over the JSPLIT window-partials, then block sums.
__global__ __launch_bounds__(1024) void chamfer_reduce(
    const float* __restrict__ pm, float* __restrict__ bsums)
{
    const int sIdx = blockIdx.x * 1024 + threadIdx.x;   // 0..65535
    const int bz = sIdx >> 13;
    const int i  = sIdx & (NN - 1);
    const float* base = pm + (size_t)bz * JSPLIT * NN + i;
    float mn = base[0];
    #pragma unroll
    for (int js = 1; js < JSPLIT; ++js)
        mn = fminf(mn, base[(size_t)js * NN]);          // coalesced per js

    float ssum = mn;
    #pragma unroll
    for (int off = 32; off; off >>= 1) ssum += __shfl_down(ssum, off);

    __shared__ float wsum[16];
    const int lane = threadIdx.x & 63, wid = threadIdx.x >> 6;
    if (lane == 0) wsum[wid] = ssum;
    __syncthreads();
    if (threadIdx.x == 0) {
        float t = 0.f;
        #pragma unroll
        for (int w = 0; w < 16; ++w) t += wsum[w];
        bsums[blockIdx.x] = t;
    }
}

// Reduce 2: one wave sums the RBLOCKS block sums. mean(d12)+mean(d21)
// = sum(all 2*B*N mins)/(B*N) since N == M.
__global__ __launch_bounds__(64) void chamfer_final(
    const float* __restrict__ bsums, float* __restrict__ out)
{
    float s = bsums[threadIdx.x];
    #pragma unroll
    for (int off = 32; off; off >>= 1) s += __shfl_down(s, off);
    if (threadIdx.x == 0) out[0] = s * (1.f / (float)NPTS);
}

extern "C" void kernel_launch(void* const* d_in, const int* in_sizes, int n_in,
                              void* d_out, int out_size, void* d_ws, size_t ws_size,
                              hipStream_t stream)
{
    const float* p1 = (const float*)d_in[0];
    const float* p2 = (const float*)d_in[1];
    float* pm    = (float*)d_ws;                         // 8*32*8192 f32 = 8 MB
    float* bsums = pm + (size_t)2 * BB * JSPLIT * NN;    // + 64 floats
    float* out   = (float*)d_out;

    dim3 grid(STILES * JSPLIT, 2 * BB);                  // 128 x 8 = 1024 blocks
    chamfer_main<<<grid, TILE, 0, stream>>>(p1, p2, pm);
    chamfer_reduce<<<RBLOCKS, 1024, 0, stream>>>(pm, bsums);
    chamfer_final<<<1, 64, 0, stream>>>(bsums, out);
}